// Round 3
// baseline (153.641 us; speedup 1.0000x reference)
//
#include <hip/hip_runtime.h>

#define WAVE 64
#define SEGS_PER_BLOCK 4   // 4 waves per 256-thread block, one wave per segment

// ---------------------------------------------------------------------------
// Single fused kernel. Block b owns segments [4b, 4b+4). Threads 0..4 binary-
// search the sorted batch array for the 5 segment boundaries (lower_bound),
// share them through LDS; then each wave accumulates its contiguous segment
// with coalesced float4 loads, tree-reduces, and lane 0 applies the tiny
// 5->5->1 MLP and writes out[seg]. No atomics, no workspace, one dispatch.
// ---------------------------------------------------------------------------
__global__ void __launch_bounds__(256)
fused_segmean_mlp_kernel(const float4* __restrict__ x,
                         const int* __restrict__ batch,
                         const float* __restrict__ u,
                         const float* __restrict__ W1,   // [5,5] row-major
                         const float* __restrict__ b1,   // [5]
                         const float* __restrict__ W2,   // [5]
                         const float* __restrict__ b2,   // [1]
                         float* __restrict__ out,
                         int N, int B) {
    __shared__ int bounds[SEGS_PER_BLOCK + 1];

    const int seg_base = blockIdx.x * SEGS_PER_BLOCK;
    const int t = threadIdx.x;

    // Phase 1: 5 boundary searches (lower_bound: first i with batch[i] >= tgt).
    if (t <= SEGS_PER_BLOCK) {
        const int target = seg_base + t;
        int lo = 0, hi = N;
        while (lo < hi) {
            int mid = (lo + hi) >> 1;
            if (batch[mid] < target) lo = mid + 1; else hi = mid;
        }
        bounds[t] = lo;
    }
    __syncthreads();

    // Phase 2: one wave per segment.
    const int wv   = t / WAVE;            // 0..3
    const int lane = t & (WAVE - 1);
    const int wid  = seg_base + wv;
    if (wid >= B) return;

    const int start = bounds[wv];
    const int end   = bounds[wv + 1];

    float4 acc = make_float4(0.f, 0.f, 0.f, 0.f);
    for (int i = start + lane; i < end; i += WAVE) {
        float4 v = x[i];
        acc.x += v.x; acc.y += v.y; acc.z += v.z; acc.w += v.w;
    }

    #pragma unroll
    for (int off = 32; off > 0; off >>= 1) {
        acc.x += __shfl_down(acc.x, off);
        acc.y += __shfl_down(acc.y, off);
        acc.z += __shfl_down(acc.z, off);
        acc.w += __shfl_down(acc.w, off);
    }

    if (lane == 0) {
        const int cnt = end - start;
        const float inv = (cnt > 0) ? (1.0f / (float)cnt) : 0.0f;

        float h[5];
        h[0] = u[wid];
        h[1] = acc.x * inv;
        h[2] = acc.y * inv;
        h[3] = acc.z * inv;
        h[4] = acc.w * inv;

        float o = b2[0];
        #pragma unroll
        for (int j = 0; j < 5; ++j) {
            float s = b1[j];
            #pragma unroll
            for (int i = 0; i < 5; ++i) s += h[i] * W1[i * 5 + j];
            s = (s > 0.0f) ? s : 0.1f * s;   // leaky_relu, slope 0.1
            o += s * W2[j];
        }
        out[wid] = o;
    }
}

extern "C" void kernel_launch(void* const* d_in, const int* in_sizes, int n_in,
                              void* d_out, int out_size, void* d_ws, size_t ws_size,
                              hipStream_t stream) {
    const float* x     = (const float*)d_in[0];  // [N,4]
    const int*   batch = (const int*)  d_in[1];  // [N]
    const float* u     = (const float*)d_in[2];  // [B,1]
    const float* W1    = (const float*)d_in[3];  // [5,5]
    const float* b1    = (const float*)d_in[4];  // [5]
    const float* W2    = (const float*)d_in[5];  // [5,1]
    const float* b2    = (const float*)d_in[6];  // [1]
    float* out = (float*)d_out;

    const int N = in_sizes[0] / 4;
    const int B = out_size;                      // output is [B,1]

    const int blocks = (B + SEGS_PER_BLOCK - 1) / SEGS_PER_BLOCK;
    fused_segmean_mlp_kernel<<<blocks, 256, 0, stream>>>(
        (const float4*)x, batch, u, W1, b1, W2, b2, out, N, B);
}

// Round 4
// 143.939 us; speedup vs baseline: 1.0674x; 1.0674x over previous
//
#include <hip/hip_runtime.h>

#define WAVE 64

// ---------------------------------------------------------------------------
// Kernel A: segment start offsets from the sorted batch index, vectorized.
// seg_start[s] = min{ i : batch[i] >= s } for s in [0,B]; seg_start[B] = N.
// Each thread handles a quad of elements via one int4 load; the quad's
// predecessor element comes from an L1-resident scalar load. Every s in
// [0,B] is written exactly once -> no initialization needed (poison-immune).
// ---------------------------------------------------------------------------
__global__ void find_starts4_kernel(const int* __restrict__ batch,
                                    int* __restrict__ seg_start,
                                    int N, int B) {
    const int tid = blockIdx.x * blockDim.x + threadIdx.x;
    const long long i0 = (long long)tid * 4;
    if (i0 >= N) return;

    int prev = (i0 == 0) ? -1 : batch[i0 - 1];

    if (i0 + 3 < N) {
        int4 q = ((const int4*)batch)[tid];
        int e[4] = {q.x, q.y, q.z, q.w};
        #pragma unroll
        for (int k = 0; k < 4; ++k) {
            int cur = e[k];
            for (int s = prev + 1; s <= cur; ++s) seg_start[s] = (int)(i0 + k);
            prev = cur;
        }
    } else {
        for (long long j = i0; j < N; ++j) {
            int cur = batch[j];
            for (int s = prev + 1; s <= cur; ++s) seg_start[s] = (int)j;
            prev = cur;
        }
    }

    if (i0 + 4 >= N) {  // owner of the final quad writes the tail sentinels
        for (int s = prev + 1; s <= B; ++s) seg_start[s] = N;
    }
}

// ---------------------------------------------------------------------------
// Kernel B: one wave per segment. Coalesced float4 accumulation over the
// segment's contiguous rows, wave tree-reduction, then lane 0 computes the
// fused MLP:  h=[u,mean] (5) -> leaky_relu(h@W1+b1) -> @W2+b2 -> out[b].
// ---------------------------------------------------------------------------
__global__ void __launch_bounds__(256)
seg_mean_mlp_kernel(const float4* __restrict__ x,
                    const int* __restrict__ seg_start,
                    const float* __restrict__ u,
                    const float* __restrict__ W1,   // [5,5] row-major
                    const float* __restrict__ b1,   // [5]
                    const float* __restrict__ W2,   // [5]
                    const float* __restrict__ b2,   // [1]
                    float* __restrict__ out, int B) {
    const int wid  = (blockIdx.x * blockDim.x + threadIdx.x) / WAVE;
    const int lane = threadIdx.x & (WAVE - 1);
    if (wid >= B) return;

    const int start = seg_start[wid];
    const int end   = seg_start[wid + 1];

    float4 acc = make_float4(0.f, 0.f, 0.f, 0.f);
    for (int i = start + lane; i < end; i += WAVE) {
        float4 v = x[i];
        acc.x += v.x; acc.y += v.y; acc.z += v.z; acc.w += v.w;
    }

    #pragma unroll
    for (int off = 32; off > 0; off >>= 1) {
        acc.x += __shfl_down(acc.x, off);
        acc.y += __shfl_down(acc.y, off);
        acc.z += __shfl_down(acc.z, off);
        acc.w += __shfl_down(acc.w, off);
    }

    if (lane == 0) {
        const int cnt = end - start;
        const float inv = (cnt > 0) ? (1.0f / (float)cnt) : 0.0f;

        float h[5];
        h[0] = u[wid];
        h[1] = acc.x * inv;
        h[2] = acc.y * inv;
        h[3] = acc.z * inv;
        h[4] = acc.w * inv;

        float o = b2[0];
        #pragma unroll
        for (int j = 0; j < 5; ++j) {
            float s = b1[j];
            #pragma unroll
            for (int i = 0; i < 5; ++i) s += h[i] * W1[i * 5 + j];
            s = (s > 0.0f) ? s : 0.1f * s;   // leaky_relu, slope 0.1
            o += s * W2[j];
        }
        out[wid] = o;
    }
}

extern "C" void kernel_launch(void* const* d_in, const int* in_sizes, int n_in,
                              void* d_out, int out_size, void* d_ws, size_t ws_size,
                              hipStream_t stream) {
    const float* x     = (const float*)d_in[0];  // [N,4]
    const int*   batch = (const int*)  d_in[1];  // [N]
    const float* u     = (const float*)d_in[2];  // [B,1]
    const float* W1    = (const float*)d_in[3];  // [5,5]
    const float* b1    = (const float*)d_in[4];  // [5]
    const float* W2    = (const float*)d_in[5];  // [5,1]
    const float* b2    = (const float*)d_in[6];  // [1]
    float* out = (float*)d_out;

    const int N = in_sizes[0] / 4;
    const int B = out_size;                      // output is [B,1]

    int* seg_start = (int*)d_ws;                 // [B+1] ints, fully rewritten

    const int quads = (N + 3) / 4;
    find_starts4_kernel<<<(quads + 255) / 256, 256, 0, stream>>>(batch, seg_start, N, B);

    const int threads = 256;
    const int blocks  = ((long long)B * WAVE + threads - 1) / threads;
    seg_mean_mlp_kernel<<<blocks, threads, 0, stream>>>(
        (const float4*)x, seg_start, u, W1, b1, W2, b2, out, B);
}

// Round 5
// 141.420 us; speedup vs baseline: 1.0864x; 1.0178x over previous
//
#include <hip/hip_runtime.h>

#define WAVE 64

// ---------------------------------------------------------------------------
// Kernel A: segment start offsets from the sorted batch index, vectorized.
// seg_start[s] = min{ i : batch[i] >= s } for s in [0,B]; seg_start[B] = N.
// One int4 per thread; the quad's predecessor element comes from the
// neighbor lane via __shfl_up (only lane 0 of each wave loads it).
// Every s in [0,B] is written exactly once -> no init needed (poison-immune).
// ---------------------------------------------------------------------------
__global__ void find_starts4_kernel(const int* __restrict__ batch,
                                    int* __restrict__ seg_start,
                                    int N, int B) {
    const int tid  = blockIdx.x * blockDim.x + threadIdx.x;
    const int lane = threadIdx.x & (WAVE - 1);
    const long long i0 = (long long)tid * 4;
    const bool in   = (i0 < N);
    const bool full = (i0 + 3 < N);

    int4 q = make_int4(0, 0, 0, 0);
    if (full) q = ((const int4*)batch)[tid];

    // Predecessor of this quad = last element of the previous thread's quad.
    // All threads participate in the shuffle before any early exit.
    int prevw = __shfl_up(q.w, 1);

    if (!in) return;

    int prev;
    if (lane == 0) prev = (i0 == 0) ? -1 : batch[i0 - 1];
    else           prev = prevw;      // predecessor quad is always full here

    if (full) {
        int e[4] = {q.x, q.y, q.z, q.w};
        #pragma unroll
        for (int k = 0; k < 4; ++k) {
            int cur = e[k];
            for (int s = prev + 1; s <= cur; ++s) seg_start[s] = (int)(i0 + k);
            prev = cur;
        }
    } else {
        for (long long j = i0; j < N; ++j) {
            int cur = batch[j];
            for (int s = prev + 1; s <= cur; ++s) seg_start[s] = (int)j;
            prev = cur;
        }
    }

    if (i0 + 4 >= N) {  // owner of the final quad writes the tail sentinels
        for (int s = prev + 1; s <= B; ++s) seg_start[s] = N;
    }
}

// ---------------------------------------------------------------------------
// Kernel B: one wave per segment. Coalesced float4 accumulation (2x unrolled,
// dual accumulators for 2 loads in flight), wave tree-reduction, then lane 0
// computes the fused MLP: h=[u,mean] -> leaky_relu(h@W1+b1) -> @W2+b2.
// ---------------------------------------------------------------------------
__global__ void __launch_bounds__(256)
seg_mean_mlp_kernel(const float4* __restrict__ x,
                    const int* __restrict__ seg_start,
                    const float* __restrict__ u,
                    const float* __restrict__ W1,   // [5,5] row-major
                    const float* __restrict__ b1,   // [5]
                    const float* __restrict__ W2,   // [5]
                    const float* __restrict__ b2,   // [1]
                    float* __restrict__ out, int B) {
    const int wid  = (blockIdx.x * blockDim.x + threadIdx.x) / WAVE;
    const int lane = threadIdx.x & (WAVE - 1);
    if (wid >= B) return;

    const int start = seg_start[wid];
    const int end   = seg_start[wid + 1];

    float4 a0 = make_float4(0.f, 0.f, 0.f, 0.f);
    float4 a1 = make_float4(0.f, 0.f, 0.f, 0.f);

    int i = start + lane;
    for (; i + WAVE < end; i += 2 * WAVE) {
        float4 v0 = x[i];
        float4 v1 = x[i + WAVE];
        a0.x += v0.x; a0.y += v0.y; a0.z += v0.z; a0.w += v0.w;
        a1.x += v1.x; a1.y += v1.y; a1.z += v1.z; a1.w += v1.w;
    }
    if (i < end) {
        float4 v = x[i];
        a0.x += v.x; a0.y += v.y; a0.z += v.z; a0.w += v.w;
    }
    a0.x += a1.x; a0.y += a1.y; a0.z += a1.z; a0.w += a1.w;

    #pragma unroll
    for (int off = 32; off > 0; off >>= 1) {
        a0.x += __shfl_down(a0.x, off);
        a0.y += __shfl_down(a0.y, off);
        a0.z += __shfl_down(a0.z, off);
        a0.w += __shfl_down(a0.w, off);
    }

    if (lane == 0) {
        const int cnt = end - start;
        const float inv = (cnt > 0) ? (1.0f / (float)cnt) : 0.0f;

        float h[5];
        h[0] = u[wid];
        h[1] = a0.x * inv;
        h[2] = a0.y * inv;
        h[3] = a0.z * inv;
        h[4] = a0.w * inv;

        float o = b2[0];
        #pragma unroll
        for (int j = 0; j < 5; ++j) {
            float s = b1[j];
            #pragma unroll
            for (int i2 = 0; i2 < 5; ++i2) s += h[i2] * W1[i2 * 5 + j];
            s = (s > 0.0f) ? s : 0.1f * s;   // leaky_relu, slope 0.1
            o += s * W2[j];
        }
        out[wid] = o;
    }
}

extern "C" void kernel_launch(void* const* d_in, const int* in_sizes, int n_in,
                              void* d_out, int out_size, void* d_ws, size_t ws_size,
                              hipStream_t stream) {
    const float* x     = (const float*)d_in[0];  // [N,4]
    const int*   batch = (const int*)  d_in[1];  // [N]
    const float* u     = (const float*)d_in[2];  // [B,1]
    const float* W1    = (const float*)d_in[3];  // [5,5]
    const float* b1    = (const float*)d_in[4];  // [5]
    const float* W2    = (const float*)d_in[5];  // [5,1]
    const float* b2    = (const float*)d_in[6];  // [1]
    float* out = (float*)d_out;

    const int N = in_sizes[0] / 4;
    const int B = out_size;                      // output is [B,1]

    int* seg_start = (int*)d_ws;                 // [B+1] ints, fully rewritten

    const int quads = (N + 3) / 4;
    find_starts4_kernel<<<(quads + 255) / 256, 256, 0, stream>>>(batch, seg_start, N, B);

    const int threads = 256;
    const int blocks  = (int)(((long long)B * WAVE + threads - 1) / threads);
    seg_mean_mlp_kernel<<<blocks, threads, 0, stream>>>(
        (const float4*)x, seg_start, u, W1, b1, W2, b2, out, B);
}